// Round 8
// baseline (11522.939 us; speedup 1.0000x reference)
//
#include <hip/hip_runtime.h>
#include <math.h>

namespace {

constexpr int N_   = 200;   // nodes
constexpr int H_   = 20;    // inner steps
constexpr int B_   = 400;   // outer steps
constexpr int OUT_ = 64;    // eeg channels
constexpr int BUF_ = 500;   // hE buffer length
constexpr int NT_  = 1024;  // 16 waves, single persistent workgroup
constexpr int HD_  = 50;    // history depth (max delay 49)
constexpr int HS_  = 51;    // transposed history stride (histT[j*HS_+c])
constexpr int GT0  = 224;   // first gather thread
constexpr int NG_  = 800;   // gather threads (4 per row)
constexpr int EPT  = 50;    // entries per gather thread
constexpr int CAP  = 16;    // CSR capacity (d==0 / d==1)
constexpr int UNR  = 12;    // unrolled CSR entries

constexpr float L2E = 1.4426950408889634f;
constexpr float LN2 = 0.6931471805599453f;

constexpr float DT_  = 0.0001f;
constexpr float G_   = 1000.01f;
constexpr float C1_  = 135.01f;
constexpr float C2_  = 108.01f;
constexpr float C3_  = 33.76f;
constexpr float C4_  = 33.76f;
constexpr float STD_ = 250.0f;
constexpr float K_   = 5.5f;
constexpr float CY0_ = 5.0f;
constexpr float Y0_  = 2.0f;

constexpr float RL2E = 0.56f * L2E;
constexpr float V0R  = 6.0f * RL2E;
constexpr float TU_  = 2.0f * L2E / 500.0f;
constexpr float TS_  = 2.0f * L2E / 1000.0f;

// ddXv = Xv + DT*(A*a*u - 2a*Xv - a^2*X)
constexpr float KMv = 0.9798f, KMu = 0.0328250f, KMx = 1.0201f;
constexpr float KEv = 0.9798f, KEu = 0.0328250f, KEx = 1.0201f;
constexpr float KIv = 0.9898f, KIu = 0.1122000f, KIx = 0.2601f;

__device__ __forceinline__ float fexp2(float x){ return __builtin_amdgcn_exp2f(x); }
__device__ __forceinline__ float flog2(float x){ return __builtin_amdgcn_logf(x); }
__device__ __forceinline__ float frcp (float x){ return __builtin_amdgcn_rcpf(x); }

__device__ __forceinline__ float sigf(float x){
    return 5.0f * frcp(1.0f + fexp2(fmaf(-RL2E, x, V0R)));
}
__device__ __forceinline__ float tanh500(float x){
    return 500.0f - 1000.0f * frcp(1.0f + fexp2(x * TU_));
}
__device__ __forceinline__ float satf(float x){
    return 1000.0f - 2000.0f * frcp(1.0f + fexp2(x * TS_));
}
__device__ __forceinline__ float wl_f(const float* __restrict__ wbb,
                                      const float* __restrict__ sc,
                                      int i, int j){
    float w0 = fexp2(wbb[i*N_+j]*L2E) * sc[i*N_+j];
    float w1 = fexp2(wbb[j*N_+i]*L2E) * sc[j*N_+i];
    return flog2(1.0f + 0.5f*(w0+w1)) * LN2;
}

// Key structure (R8): 3 inner steps per barrier. Cross-step coupling is only
// via each node's M through the ~6-entry d==0 CSR, and M's 2-step future is
// computable bitwise-identically from a (M,Mv,E-I) snapshot:
//   M1 = sat(fma(DT,Mv,M)); Mv1 = sat(fma(KMv,Mv,fma(KMu,tanh500(sig(EmI)),-KMx*M)));
//   M2 = sat(fma(DT,Mv1,M1))        [M3 would need EmI1 -> 3 steps is the max]
// So rows read one ds_read_b128 snapshot per CSR entry and serve steps A/B/C
// from it: barriers/outer 22 -> 9, row DS instructions/step about -35%.
__global__ void __launch_bounds__(NT_)
jansen_kernel(
    const float* __restrict__ input,     // (N,H,B)
    const float* __restrict__ noise_in,  // (N,H,B,3)
    const float* __restrict__ hx,        // (N,6)
    const float* __restrict__ hEin,      // (N,500)
    const float* __restrict__ wbb,       // (N,N)
    const float* __restrict__ lm,        // (64,N)
    const float* __restrict__ sc,        // (N,N)
    const int*   __restrict__ dist,      // (N,N)
    float* __restrict__ out,             // 64*400 eeg + N*6 state
    float2* __restrict__ tab)            // d_ws: 40000 x (w, meta)
{
    __shared__ float  histT[N_*HS_];         // transposed circular M history
    __shared__ float2 une[H_*N_];            // packed (u, noise) per step/node
    __shared__ float4 snap2[2*N_];           // ping-pong (Mcol, Mv, EmI, M)
    __shared__ float  d0w_l[CAP*N_];         // d==0 CSR weights (SoA)
    __shared__ unsigned char d0j_l[CAP*N_];  // d==0 CSR j (u8)
    __shared__ float  d1w_l[CAP*N_];         // d==1 CSR weights
    __shared__ unsigned char d1j_l[CAP*N_];  // d==1 CSR j
    __shared__ float  led_part[4*N_];        // static-gather partials
    __shared__ float  emi[N_];
    __shared__ float  colmean[N_];
    __shared__ float  lmrs[OUT_];
    __shared__ float  red_s[NT_/64];
    __shared__ float  norm_s;

    const int t = threadIdx.x;
    const bool isr = (t < N_);
    const bool isg = (t >= GT0);             // 800 gather threads
    const int  gt  = t - GT0;                // 0..799
    const int  grow  = gt >> 2;              // row 0..199
    const int  gslot = gt & 3;               // slot 0..3
    const int  jbase = gslot * EPT;          // this thread's first j
    const int  tb    = gt * EPT;             // table base index

    int sidx[5];                             // slab LDS indices (gather)
    int goff[5];                             // slab global offsets sans sn

    // ===== S0: lmrs + state/hist/snap init + initial slab (b=0) =====
    if (t < OUT_){
        float s2 = 0.f;
        for (int j=0;j<N_;++j) s2 += fabsf(lm[t*N_+j]);
        lmrs[t] = s2;
    }
    float M=0,E=0,I=0,Mv=0,Ev=0,Iv=0, rowsum=0, ledst=0;
    int cnt0=0, cnt1=0;
    #pragma unroll
    for (int r=0;r<5;++r){ sidx[r]=0; goff[r]=0; }
    if (isg){
        #pragma unroll
        for (int r=0;r<5;++r){
            int p = r*NG_ + gt;
            int hh = p / N_, ii = p - hh*N_;
            sidx[r] = hh*N_ + ii;
            goff[r] = ii*(H_*B_) + hh*B_;
            une[sidx[r]] = make_float2(input[goff[r]], noise_in[goff[r]*3]);
        }
    }
    if (isr){
        // initial hEb col k (k=1..49) -> slot (0-k) mod 50 = 50-k
        for (int k=1;k<HD_;++k) histT[t*HS_ + (HD_-k)] = hEin[t*BUF_+k];
        M=hx[t*6+0]; E=hx[t*6+1]; I=hx[t*6+2];
        Mv=hx[t*6+3]; Ev=hx[t*6+4]; Iv=hx[t*6+5];
        // snap: col0 value is hE[:,0] initially (NOT state M); state fields hx
        snap2[t] = make_float4(hEin[t*BUF_], Mv, E - I, M);
    }
    __syncthreads();

    // ===== S1: compute wl entries -> RAW table; Frobenius + rowsum =====
    float ss = 0.f, rs = 0.f;
    for (int m=0;m<EPT;++m){
        float w = 0.f; int d = 2;
        int j = jbase + m;
        if (isg){
            d = dist[j*N_+grow] >> 1;        // delays[j][grow]
            w = wl_f(wbb, sc, grow, j);
        }
        ss = fmaf(w,w,ss); rs += w;
        if (isg){
            int dm = (d<2) ? 2 : d;          // d<2 handled by CSRs
            float ws = (d>=2) ? w : 0.f;
            tab[tb+m] = make_float2(ws, __uint_as_float((unsigned)j | ((unsigned)dm<<16)));
        }
    }
    if (isr){                                 // colmean (needs lmrs)
        float cm=0.f;
        for (int o=0;o<OUT_;++o) cm += lm[o*N_+t] * frcp(lmrs[o]);
        colmean[t] = cm * (1.0f/(float)OUT_);
    }
    #pragma unroll
    for (int o=32;o>0;o>>=1) ss += __shfl_down(ss,o,64);
    if ((t&63)==0) red_s[t>>6] = ss;
    __syncthreads();
    if (t==0){ float tot=0.f; for (int w=0;w<NT_/64;++w) tot+=red_s[w]; norm_s = sqrtf(tot); }
    __syncthreads();
    const float inv = 1.0f / norm_s;
    if (isg){
        float* tf = (float*)tab;
        for (int m=0;m<EPT;++m) tf[2*(tb+m)] *= inv;
    }
    if (isg) led_part[gslot*N_+grow] = rs;    // raw rowsum partial

    // ===== S3: row CSR build (d<2), registers for d0 =====
    float dw[UNR]; unsigned jpk[3];
    #pragma unroll
    for (int k=0;k<UNR;++k) dw[k] = 0.f;
    jpk[0]=jpk[1]=jpk[2]=0u;
    if (isr){
        #pragma unroll
        for (int k=0;k<UNR;++k){ d0w_l[k*N_+t]=0.f; d0j_l[k*N_+t]=0;
                                 d1w_l[k*N_+t]=0.f; d1j_l[k*N_+t]=0; }
        for (int j=0;j<N_;++j){
            int dd = dist[j*N_+t] >> 1;
            if (dd < 2){
                float w = wl_f(wbb, sc, t, j) * inv;
                if (dd==0){ if (cnt0<CAP){ d0w_l[cnt0*N_+t]=w; d0j_l[cnt0*N_+t]=(unsigned char)j; ++cnt0; } }
                else      { if (cnt1<CAP){ d1w_l[cnt1*N_+t]=w; d1j_l[cnt1*N_+t]=(unsigned char)j; ++cnt1; } }
            }
        }
        #pragma unroll
        for (int k=0;k<UNR;++k){
            dw[k] = d0w_l[k*N_+t];
            unsigned jv = d0j_l[k*N_+t];
            jpk[k>>2] |= jv << ((k&3)*8);
        }
    }
    __syncthreads();

    // ===== S4: rowsum =====
    if (isr){
        rowsum = (led_part[t]+led_part[N_+t]+led_part[2*N_+t]+led_part[3*N_+t]) * inv;
    }
    __syncthreads();

    // ===== S5: initial static gather for s=0 (target step 0 -> c = 50-d) =====
    if (isg){
        float a0 = 0.f;
        for (int m=0;m<EPT;++m){
            float2 e = tab[tb+m];
            unsigned um = __float_as_uint(e.y);
            int c = HD_ - (int)(um>>16);     // d in [2,49] -> c in [1,48]
            a0 = fmaf(e.x, histT[(um&0xFFFFu)*HS_ + c], a0);
        }
        led_part[gslot*N_+grow] = a0;
    }
    __syncthreads();

    // ===== S6: initial ledst (+ d==1 from hE col 1 = slot 49) =====
    if (isr){
        float v = led_part[t]+led_part[N_+t]+led_part[2*N_+t]+led_part[3*N_+t];
        #pragma unroll
        for (int k=0;k<UNR;++k)
            v = fmaf(d1w_l[k*N_+t], histT[(int)d1j_l[k*N_+t]*HS_ + 49], v);
        for (int k=UNR;k<cnt1;++k)
            v = fmaf(d1w_l[k*N_+t], histT[(int)d1j_l[k*N_+t]*HS_ + 49], v);
        ledst = v;
    }
    __syncthreads();

// one ODE inner step; LEd and (u,ne) given
#define STEP(LEDV, UN) do{                                                   \
    float rM  = sigf(E - I);                                                 \
    float uM  = tanh500(rM);                                                 \
    float Mn  = satf(fmaf(DT_, Mv, M));                                      \
    float Mvn = satf(fmaf(KMv, Mv, fmaf(KMu, uM, -KMx*M)));                  \
    float rI  = C4_*sigf(C3_*M);                                             \
    float uI  = tanh500(rI);                                                 \
    float In  = satf(fmaf(DT_, Iv, I));                                      \
    float Ivn = satf(fmaf(KIv, Iv, fmaf(KIu, uI, -KIx*I)));                  \
    float rE  = fmaf(STD_, (UN).y, G_*((LEDV) - rowsum*E)) + C2_*sigf(C1_*M);\
    float uE  = fmaf(K_, (UN).x, tanh500(rE));                               \
    float En  = satf(fmaf(DT_, Ev, E));                                      \
    float Evn = satf(fmaf(KEv, Ev, fmaf(KEu, uE, -KEx*E)));                  \
    M=Mn; Mv=Mvn; I=In; Iv=Ivn; E=En; Ev=Evn;                                \
}while(0)

// neighbor replication: from snapshot sj produce col0 contributions for
// steps A (sj.x), B (Mj1), C (Mj2) — bitwise-identical to node j's own ops
#define REP(W, SJ, LA, LB, LC) do{                                           \
    float Mj1  = satf(fmaf(DT_, (SJ).y, (SJ).w));                            \
    float uMj  = tanh500(sigf((SJ).z));                                      \
    float Mvj1 = satf(fmaf(KMv, (SJ).y, fmaf(KMu, uMj, -KMx*(SJ).w)));       \
    float Mj2  = satf(fmaf(DT_, Mvj1, Mj1));                                 \
    LA = fmaf((W), (SJ).x, LA);                                              \
    LB = fmaf((W), Mj1,    LB);                                              \
    LC = fmaf((W), Mj2,    LC);                                              \
}while(0)

    // ===== main loop: 400 outer x 7 blocks (3+3+3+3+3+3+2 inner steps) =====
    int smod = 0;
    int pp = 0;                              // snap2 buffer holding latest state
    for (int s=0; s<B_; ++s){
        int ts = smod+1; if (ts==HD_) ts = 0;      // (s+1) % 50
        float acc = 0.f;
        for (int q=0; q<7; ++q){
            const int h0  = 3*q;
            const bool full = (q < 6);             // 3-step block vs 2-step tail
            // --- gather: 8 (or 2) static entries for outer step s+1 ---
            if (isg){
                const int mb = q*8;
                #pragma unroll
                for (int k=0;k<8;++k){
                    if (full || k<2){
                        float2 e = tab[tb+mb+k];
                        unsigned um = __float_as_uint(e.y);
                        int c = ts - (int)(um>>16); if (c<0) c += HD_;
                        acc = fmaf(e.x, histT[(um&0xFFFFu)*HS_ + c], acc);
                    }
                }
            }
            if (isr){
                const float4* sr = &snap2[pp*N_];
                float4*       sw = &snap2[(pp^1)*N_];
                float2 un0 = une[(h0+0)*N_+t];
                float2 un1 = une[(h0+1)*N_+t];
                float2 un2 = full ? une[(h0+2)*N_+t] : make_float2(0.f,0.f);
                // CSR pass: one b128 per entry serves all 3 steps
                float lA0=0,lA1=0,lB0=0,lB1=0,lC0=0,lC1=0;
                #pragma unroll
                for (int k=0;k<UNR;++k){
                    int j = (jpk[k>>2] >> ((k&3)*8)) & 255;
                    float w = dw[k];
                    float4 sj = sr[j];
                    if (k&1) REP(w, sj, lA1, lB1, lC1);
                    else     REP(w, sj, lA0, lB0, lC0);
                }
                for (int k=UNR;k<cnt0;++k){
                    float w = d0w_l[k*N_+t];
                    float4 sj = sr[d0j_l[k*N_+t]];
                    REP(w, sj, lA0, lB0, lC0);
                }
                float LA = ledst + (lA0+lA1);
                float LB = ledst + (lB0+lB1);
                float LC = ledst + (lC0+lC1);
                STEP(LA, un0);
                STEP(LB, un1);
                if (full) STEP(LC, un2);
                sw[t] = make_float4(M, Mv, E - I, M);
            }
            __syncthreads();
            pp ^= 1;
        }
        // ===== outer boundary =====
        if (isr){ histT[t*HS_ + smod] = M; emi[t] = E - I; }
        if (isg){
            led_part[gslot*N_+grow] = acc;
            // stage (u,ne) slab for s+1 (one L2 drain per outer step)
            int sn = s+1; if (sn >= B_) sn = B_-1;
            #pragma unroll
            for (int r=0;r<5;++r){
                une[sidx[r]] = make_float2(input[goff[r] + sn],
                                           noise_in[(goff[r] + sn)*3]);
            }
        }
        __syncthreads();
        if (isr){
            float v = led_part[t]+led_part[N_+t]+led_part[2*N_+t]+led_part[3*N_+t];
            // d==1 term: col 1 during s+1 = M_end(s) = latest snap .w
            const float4* sp = &snap2[pp*N_];
            #pragma unroll
            for (int k=0;k<UNR;++k)
                v = fmaf(d1w_l[k*N_+t], sp[d1j_l[k*N_+t]].w, v);
            for (int k=UNR;k<cnt1;++k)
                v = fmaf(d1w_l[k*N_+t], sp[d1j_l[k*N_+t]].w, v);
            ledst = v;
        }
        {   // eeg
            int o = t>>4, l = t&15;
            float il = frcp(lmrs[o]);
            float a2 = 0.f;
            for (int j=l;j<N_;j+=16)
                a2 = fmaf(fmaf(lm[o*N_+j], il, -colmean[j]), emi[j], a2);
            a2 += __shfl_down(a2,8,16); a2 += __shfl_down(a2,4,16);
            a2 += __shfl_down(a2,2,16); a2 += __shfl_down(a2,1,16);
            if (l==0) out[o*B_+s] = fmaf(CY0_, a2, -Y0_);
        }
        smod = ts;
        __syncthreads();
    }

#undef STEP
#undef REP

    // final state
    if (isr){
        float* cs = out + OUT_*B_ + t*6;
        cs[0]=M; cs[1]=E; cs[2]=I; cs[3]=Mv; cs[4]=Ev; cs[5]=Iv;
    }
}

} // namespace

extern "C" void kernel_launch(void* const* d_in, const int* in_sizes, int n_in,
                              void* d_out, int out_size, void* d_ws, size_t ws_size,
                              hipStream_t stream)
{
    const float* input    = (const float*)d_in[0];
    const float* noise_in = (const float*)d_in[1];
    const float* hx   = (const float*)d_in[3];
    const float* hEin = (const float*)d_in[4];
    const float* wbb  = (const float*)d_in[5];
    const float* lm   = (const float*)d_in[6];
    const float* sc   = (const float*)d_in[7];
    const int*   dist = (const int*)d_in[8];
    float* out = (float*)d_out;
    float2* tab = (float2*)((char*)d_ws + 1024);   // 40000 x 8B = 320KB

    hipLaunchKernelGGL(jansen_kernel, dim3(1), dim3(NT_), 0, stream,
                       input, noise_in, hx, hEin, wbb, lm, sc, dist, out, tab);
}

// Round 9
// 9748.240 us; speedup vs baseline: 1.1821x; 1.1821x over previous
//
#include <hip/hip_runtime.h>
#include <math.h>

namespace {

constexpr int N_   = 200;   // nodes
constexpr int H_   = 20;    // inner steps
constexpr int B_   = 400;   // outer steps
constexpr int OUT_ = 64;    // eeg channels
constexpr int BUF_ = 500;   // hE buffer length
constexpr int NT_  = 1024;  // 16 waves, single persistent workgroup
constexpr int HD_  = 50;    // history depth (max delay 49)
constexpr int HS_  = 51;    // transposed history stride (histT[j*HS_+c])
constexpr int GT0  = 224;   // first gather thread
constexpr int NG_  = 800;   // gather threads (4 per row)
constexpr int EPT  = 50;    // entries per gather thread
constexpr int CAP  = 16;    // CSR capacity (d==0 / d==1)
constexpr int UNR  = 12;    // unrolled CSR entries

constexpr float L2E = 1.4426950408889634f;
constexpr float LN2 = 0.6931471805599453f;

constexpr float DT_  = 0.0001f;
constexpr float G_   = 1000.01f;
constexpr float C1_  = 135.01f;
constexpr float C2_  = 108.01f;
constexpr float C3_  = 33.76f;
constexpr float C4_  = 33.76f;
constexpr float STD_ = 250.0f;
constexpr float K_   = 5.5f;
constexpr float CY0_ = 5.0f;
constexpr float Y0_  = 2.0f;

constexpr float RL2E = 0.56f * L2E;
constexpr float V0R  = 6.0f * RL2E;
constexpr float TU_  = 2.0f * L2E / 500.0f;
constexpr float TS_  = 2.0f * L2E / 1000.0f;

// ddXv = Xv + DT*(A*a*u - 2a*Xv - a^2*X)
constexpr float KMv = 0.9798f, KMu = 0.0328250f, KMx = 1.0201f;
constexpr float KEv = 0.9798f, KEu = 0.0328250f, KEx = 1.0201f;
constexpr float KIv = 0.9898f, KIu = 0.1122000f, KIx = 0.2601f;

__device__ __forceinline__ float fexp2(float x){ return __builtin_amdgcn_exp2f(x); }
__device__ __forceinline__ float flog2(float x){ return __builtin_amdgcn_logf(x); }
__device__ __forceinline__ float frcp (float x){ return __builtin_amdgcn_rcpf(x); }

__device__ __forceinline__ float sigf(float x){
    return 5.0f * frcp(1.0f + fexp2(fmaf(-RL2E, x, V0R)));
}
__device__ __forceinline__ float tanh500(float x){
    return 500.0f - 1000.0f * frcp(1.0f + fexp2(x * TU_));
}
__device__ __forceinline__ float satf(float x){
    return 1000.0f - 2000.0f * frcp(1.0f + fexp2(x * TS_));
}
__device__ __forceinline__ float wl_f(const float* __restrict__ wbb,
                                      const float* __restrict__ sc,
                                      int i, int j){
    float w0 = fexp2(wbb[i*N_+j]*L2E) * sc[i*N_+j];
    float w1 = fexp2(wbb[j*N_+i]*L2E) * sc[j*N_+i];
    return flog2(1.0f + 0.5f*(w0+w1)) * LN2;
}

// R9 structure: 3 inner steps per barrier via OWNER-side M replication.
// From state S_h a node can compute its own M_{h+1}, M_{h+2} exactly
// (~10 VALU per ROW, vs R8's per-ENTRY replication = 170 VALU + spills).
// Each row publishes (M_h, M_{h+1}, M_{h+2}) as one float4; CSR consumers
// read one ds_read_b128 per entry for all 3 steps. Barriers/outer 22 -> 8.
__global__ void __launch_bounds__(NT_)
jansen_kernel(
    const float* __restrict__ input,     // (N,H,B)
    const float* __restrict__ noise_in,  // (N,H,B,3)
    const float* __restrict__ hx,        // (N,6)
    const float* __restrict__ hEin,      // (N,500)
    const float* __restrict__ wbb,       // (N,N)
    const float* __restrict__ lm,        // (64,N)
    const float* __restrict__ sc,        // (N,N)
    const int*   __restrict__ dist,      // (N,N)
    float* __restrict__ out,             // 64*400 eeg + N*6 state
    float2* __restrict__ tab)            // d_ws: 40000 x (w, meta)
{
    __shared__ float  histT[N_*HS_];         // transposed circular M history
    __shared__ float2 une[H_*N_];            // packed (u, noise) per step/node
    __shared__ float4 mpub[2*N_];            // ping-pong (M_h, M_h+1, M_h+2, 0)
    __shared__ float  d0w_l[CAP*N_];         // d==0 CSR weights (SoA)
    __shared__ unsigned char d0j_l[CAP*N_];  // d==0 CSR j (u8)
    __shared__ float  d1w_l[CAP*N_];         // d==1 CSR weights
    __shared__ unsigned char d1j_l[CAP*N_];  // d==1 CSR j
    __shared__ float  led_part[4*N_];        // static-gather partials
    __shared__ float  emi[N_];
    __shared__ float  colmean[N_];
    __shared__ float  lmrs[OUT_];
    __shared__ float  red_s[NT_/64];
    __shared__ float  norm_s;

    const int t = threadIdx.x;
    const bool isr = (t < N_);
    const bool isg = (t >= GT0);             // 800 gather threads
    const int  gt  = t - GT0;                // 0..799
    const int  grow  = gt >> 2;              // row 0..199
    const int  gslot = gt & 3;               // slot 0..3
    const int  jbase = gslot * EPT;          // this thread's first j
    const int  tb    = gt * EPT;             // table base index

    int sidx[5];                             // slab LDS indices (gather)
    int goff[5];                             // slab global offsets sans sn

    // ===== S0: lmrs + state/hist init + initial slab + initial publish =====
    if (t < OUT_){
        float s2 = 0.f;
        for (int j=0;j<N_;++j) s2 += fabsf(lm[t*N_+j]);
        lmrs[t] = s2;
    }
    float M=0,E=0,I=0,Mv=0,Ev=0,Iv=0, rowsum=0, ledst=0;
    int cnt0=0, cnt1=0;
    #pragma unroll
    for (int r=0;r<5;++r){ sidx[r]=0; goff[r]=0; }
    if (isg){
        #pragma unroll
        for (int r=0;r<5;++r){
            int p = r*NG_ + gt;
            int hh = p / N_, ii = p - hh*N_;
            sidx[r] = hh*N_ + ii;
            goff[r] = ii*(H_*B_) + hh*B_;
            une[sidx[r]] = make_float2(input[goff[r]], noise_in[goff[r]*3]);
        }
    }
    if (isr){
        // initial hEb col k (k=1..49) -> slot (0-k) mod 50 = 50-k
        for (int k=1;k<HD_;++k) histT[t*HS_ + (HD_-k)] = hEin[t*BUF_+k];
        M=hx[t*6+0]; E=hx[t*6+1]; I=hx[t*6+2];
        Mv=hx[t*6+3]; Ev=hx[t*6+4]; Iv=hx[t*6+5];
        // initial publish: step0 col0 = hE[:,0] (quirk); steps 1,2 = M1,M2
        float Mp1 = satf(fmaf(DT_, Mv, M));
        float uMp = tanh500(sigf(E - I));
        float Mvp = satf(fmaf(KMv, Mv, fmaf(KMu, uMp, -KMx*M)));
        float Mp2 = satf(fmaf(DT_, Mvp, Mp1));
        mpub[t] = make_float4(hEin[t*BUF_], Mp1, Mp2, 0.f);
    }
    __syncthreads();

    // ===== S1: compute wl entries -> RAW table; Frobenius + rowsum =====
    float ss = 0.f, rs = 0.f;
    for (int m=0;m<EPT;++m){
        float w = 0.f; int d = 2;
        int j = jbase + m;
        if (isg){
            d = dist[j*N_+grow] >> 1;        // delays[j][grow]
            w = wl_f(wbb, sc, grow, j);
        }
        ss = fmaf(w,w,ss); rs += w;
        if (isg){
            int dm = (d<2) ? 2 : d;          // d<2 handled by CSRs
            float ws = (d>=2) ? w : 0.f;
            tab[tb+m] = make_float2(ws, __uint_as_float((unsigned)j | ((unsigned)dm<<16)));
        }
    }
    if (isr){                                 // colmean (needs lmrs)
        float cm=0.f;
        for (int o=0;o<OUT_;++o) cm += lm[o*N_+t] * frcp(lmrs[o]);
        colmean[t] = cm * (1.0f/(float)OUT_);
    }
    #pragma unroll
    for (int o=32;o>0;o>>=1) ss += __shfl_down(ss,o,64);
    if ((t&63)==0) red_s[t>>6] = ss;
    __syncthreads();
    if (t==0){ float tot=0.f; for (int w=0;w<NT_/64;++w) tot+=red_s[w]; norm_s = sqrtf(tot); }
    __syncthreads();
    const float inv = 1.0f / norm_s;
    if (isg){
        float* tf = (float*)tab;
        for (int m=0;m<EPT;++m) tf[2*(tb+m)] *= inv;
    }
    if (isg) led_part[gslot*N_+grow] = rs;    // raw rowsum partial

    // ===== S3: row CSR build (d<2), registers for d0 =====
    float dw[UNR]; unsigned jpk[3];
    #pragma unroll
    for (int k=0;k<UNR;++k) dw[k] = 0.f;
    jpk[0]=jpk[1]=jpk[2]=0u;
    if (isr){
        #pragma unroll
        for (int k=0;k<UNR;++k){ d0w_l[k*N_+t]=0.f; d0j_l[k*N_+t]=0;
                                 d1w_l[k*N_+t]=0.f; d1j_l[k*N_+t]=0; }
        for (int j=0;j<N_;++j){
            int dd = dist[j*N_+t] >> 1;
            if (dd < 2){
                float w = wl_f(wbb, sc, t, j) * inv;
                if (dd==0){ if (cnt0<CAP){ d0w_l[cnt0*N_+t]=w; d0j_l[cnt0*N_+t]=(unsigned char)j; ++cnt0; } }
                else      { if (cnt1<CAP){ d1w_l[cnt1*N_+t]=w; d1j_l[cnt1*N_+t]=(unsigned char)j; ++cnt1; } }
            }
        }
        #pragma unroll
        for (int k=0;k<UNR;++k){
            dw[k] = d0w_l[k*N_+t];
            unsigned jv = d0j_l[k*N_+t];
            jpk[k>>2] |= jv << ((k&3)*8);
        }
    }
    __syncthreads();

    // ===== S4: rowsum =====
    if (isr){
        rowsum = (led_part[t]+led_part[N_+t]+led_part[2*N_+t]+led_part[3*N_+t]) * inv;
    }
    __syncthreads();

    // ===== S5: initial static gather for s=0 (target step 0 -> c = 50-d) =====
    if (isg){
        float a0 = 0.f;
        for (int m=0;m<EPT;++m){
            float2 e = tab[tb+m];
            unsigned um = __float_as_uint(e.y);
            int c = HD_ - (int)(um>>16);     // d in [2,49] -> c in [1,48]
            a0 = fmaf(e.x, histT[(um&0xFFFFu)*HS_ + c], a0);
        }
        led_part[gslot*N_+grow] = a0;
    }
    __syncthreads();

    // ===== S6: initial ledst (+ d==1 from hE col 1 = slot 49) =====
    if (isr){
        float v = led_part[t]+led_part[N_+t]+led_part[2*N_+t]+led_part[3*N_+t];
        #pragma unroll
        for (int k=0;k<UNR;++k)
            v = fmaf(d1w_l[k*N_+t], histT[(int)d1j_l[k*N_+t]*HS_ + (HD_-1)], v);
        for (int k=UNR;k<cnt1;++k)
            v = fmaf(d1w_l[k*N_+t], histT[(int)d1j_l[k*N_+t]*HS_ + (HD_-1)], v);
        ledst = v;
    }
    __syncthreads();

// one ODE inner step; LEd and (u,ne) given  (bitwise-identical to R7/R8)
#define STEP(LEDV, UN) do{                                                   \
    float rM  = sigf(E - I);                                                 \
    float uM  = tanh500(rM);                                                 \
    float Mn  = satf(fmaf(DT_, Mv, M));                                      \
    float Mvn = satf(fmaf(KMv, Mv, fmaf(KMu, uM, -KMx*M)));                  \
    float rI  = C4_*sigf(C3_*M);                                             \
    float uI  = tanh500(rI);                                                 \
    float In  = satf(fmaf(DT_, Iv, I));                                      \
    float Ivn = satf(fmaf(KIv, Iv, fmaf(KIu, uI, -KIx*I)));                  \
    float rE  = fmaf(STD_, (UN).y, G_*((LEDV) - rowsum*E)) + C2_*sigf(C1_*M);\
    float uE  = fmaf(K_, (UN).x, tanh500(rE));                               \
    float En  = satf(fmaf(DT_, Ev, E));                                      \
    float Evn = satf(fmaf(KEv, Ev, fmaf(KEu, uE, -KEx*E)));                  \
    M=Mn; Mv=Mvn; I=In; Iv=Ivn; E=En; Ev=Evn;                                \
}while(0)

// owner-side publish: (M_h, M_{h+1}, M_{h+2}) from current state — the
// replicated ops are bitwise-identical to the ones STEP will perform
#define PUBLISH(SW) do{                                                      \
    float Mp1 = satf(fmaf(DT_, Mv, M));                                      \
    float uMp = tanh500(sigf(E - I));                                        \
    float Mvp = satf(fmaf(KMv, Mv, fmaf(KMu, uMp, -KMx*M)));                 \
    float Mp2 = satf(fmaf(DT_, Mvp, Mp1));                                   \
    (SW)[t] = make_float4(M, Mp1, Mp2, 0.f);                                 \
}while(0)

    // ===== main loop: 400 outer x 7 intervals (3+3+3+3+3+3+2 steps) =====
    int smod = 0;
    int pp = 0;                              // mpub buffer holding current pub
    for (int s=0; s<B_; ++s){
        int ts = smod+1; if (ts==HD_) ts = 0;      // (s+1) % 50
        float acc = 0.f;
        for (int q=0; q<7; ++q){
            const int h0  = 3*q;
            const bool full = (q < 6);             // 3-step interval vs 2-step tail
            // --- gather: 8 (or 2) static entries for outer step s+1 ---
            if (isg){
                const int mb = q*8;
                float2 ee[8];
                #pragma unroll
                for (int k=0;k<8;++k)
                    if (full || k<2) ee[k] = tab[tb+mb+k];   // batched L2 loads
                #pragma unroll
                for (int k=0;k<8;++k){
                    if (full || k<2){
                        unsigned um = __float_as_uint(ee[k].y);
                        int c = ts - (int)(um>>16); if (c<0) c += HD_;
                        acc = fmaf(ee[k].x, histT[(um&0xFFFFu)*HS_ + c], acc);
                    }
                }
            }
            if (isr){
                const float4* sr = &mpub[pp*N_];
                float4*       sw = &mpub[(pp^1)*N_];
                float2 un0 = une[(h0+0)*N_+t];
                float2 un1 = une[(h0+1)*N_+t];
                float2 un2 = full ? une[(h0+2)*N_+t] : make_float2(0.f,0.f);
                // CSR pass: one b128 per entry serves all 3 steps
                float lA=0.f, lB=0.f, lC=0.f;
                #pragma unroll
                for (int k=0;k<UNR;++k){
                    int j = (jpk[k>>2] >> ((k&3)*8)) & 255;
                    float w = dw[k];
                    float4 sj = sr[j];
                    lA = fmaf(w, sj.x, lA);
                    lB = fmaf(w, sj.y, lB);
                    lC = fmaf(w, sj.z, lC);
                }
                for (int k=UNR;k<cnt0;++k){
                    float w = d0w_l[k*N_+t];
                    float4 sj = sr[d0j_l[k*N_+t]];
                    lA = fmaf(w, sj.x, lA);
                    lB = fmaf(w, sj.y, lB);
                    lC = fmaf(w, sj.z, lC);
                }
                STEP(ledst + lA, un0);
                STEP(ledst + lB, un1);
                if (full) STEP(ledst + lC, un2);
                PUBLISH(sw);
            }
            __syncthreads();
            pp ^= 1;
        }
        // ===== outer boundary (single barrier) =====
        if (isr){ histT[t*HS_ + smod] = M; emi[t] = E - I; }
        if (isg){
            led_part[gslot*N_+grow] = acc;
            // stage (u,ne) slab for s+1 (one L2 drain per outer step)
            int sn = s+1; if (sn >= B_) sn = B_-1;
            #pragma unroll
            for (int r=0;r<5;++r){
                une[sidx[r]] = make_float2(input[goff[r] + sn],
                                           noise_in[(goff[r] + sn)*3]);
            }
        }
        __syncthreads();
        if (isr){
            float v = led_part[t]+led_part[N_+t]+led_part[2*N_+t]+led_part[3*N_+t];
            // d==1 term for outer s+1: M_end(s) = histT slot smod (just written)
            #pragma unroll
            for (int k=0;k<UNR;++k)
                v = fmaf(d1w_l[k*N_+t], histT[(int)d1j_l[k*N_+t]*HS_ + smod], v);
            for (int k=UNR;k<cnt1;++k)
                v = fmaf(d1w_l[k*N_+t], histT[(int)d1j_l[k*N_+t]*HS_ + smod], v);
            ledst = v;
        }
        {   // eeg (no trailing barrier needed: all subsequent reads are of
            // data written before the boundary barrier, or thread-private)
            int o = t>>4, l = t&15;
            float il = frcp(lmrs[o]);
            float a2 = 0.f;
            for (int j=l;j<N_;j+=16)
                a2 = fmaf(fmaf(lm[o*N_+j], il, -colmean[j]), emi[j], a2);
            a2 += __shfl_down(a2,8,16); a2 += __shfl_down(a2,4,16);
            a2 += __shfl_down(a2,2,16); a2 += __shfl_down(a2,1,16);
            if (l==0) out[o*B_+s] = fmaf(CY0_, a2, -Y0_);
        }
        smod = ts;
    }

#undef STEP
#undef PUBLISH

    // final state
    if (isr){
        float* cs = out + OUT_*B_ + t*6;
        cs[0]=M; cs[1]=E; cs[2]=I; cs[3]=Mv; cs[4]=Ev; cs[5]=Iv;
    }
}

} // namespace

extern "C" void kernel_launch(void* const* d_in, const int* in_sizes, int n_in,
                              void* d_out, int out_size, void* d_ws, size_t ws_size,
                              hipStream_t stream)
{
    const float* input    = (const float*)d_in[0];
    const float* noise_in = (const float*)d_in[1];
    const float* hx   = (const float*)d_in[3];
    const float* hEin = (const float*)d_in[4];
    const float* wbb  = (const float*)d_in[5];
    const float* lm   = (const float*)d_in[6];
    const float* sc   = (const float*)d_in[7];
    const int*   dist = (const int*)d_in[8];
    float* out = (float*)d_out;
    float2* tab = (float2*)((char*)d_ws + 1024);   // 40000 x 8B = 320KB

    hipLaunchKernelGGL(jansen_kernel, dim3(1), dim3(NT_), 0, stream,
                       input, noise_in, hx, hEin, wbb, lm, sc, dist, out, tab);
}

// Round 10
// 7448.810 us; speedup vs baseline: 1.5470x; 1.3087x over previous
//
#include <hip/hip_runtime.h>
#include <math.h>

namespace {

constexpr int N_   = 200;   // nodes
constexpr int H_   = 20;    // inner steps
constexpr int B_   = 400;   // outer steps
constexpr int OUT_ = 64;    // eeg channels
constexpr int BUF_ = 500;   // hE buffer length
constexpr int NT_  = 1024;  // 16 waves, single persistent workgroup
constexpr int HD_  = 50;    // history depth (max delay 49)
constexpr int HS_  = 51;    // transposed history stride (histT[j*HS_+c])
constexpr int GT0  = 224;   // first gather thread
constexpr int NG_  = 800;   // gather threads (4 per row)
constexpr int EPT  = 50;    // entries per gather thread
constexpr int CAP  = 16;    // CSR capacity (d==0 / d==1)
constexpr int UNR  = 12;    // unrolled CSR entries

constexpr float L2E = 1.4426950408889634f;
constexpr float LN2 = 0.6931471805599453f;

constexpr float DT_  = 0.0001f;
constexpr float G_   = 1000.01f;
constexpr float C1_  = 135.01f;
constexpr float C2_  = 108.01f;
constexpr float C3_  = 33.76f;
constexpr float C4_  = 33.76f;
constexpr float STD_ = 250.0f;
constexpr float K_   = 5.5f;
constexpr float CY0_ = 5.0f;
constexpr float Y0_  = 2.0f;

constexpr float RL2E = 0.56f * L2E;
constexpr float V0R  = 6.0f * RL2E;
constexpr float TU_  = 2.0f * L2E / 500.0f;
constexpr float TS_  = 2.0f * L2E / 1000.0f;

// ddXv = Xv + DT*(A*a*u - 2a*Xv - a^2*X)
constexpr float KMv = 0.9798f, KMu = 0.0328250f, KMx = 1.0201f;
constexpr float KEv = 0.9798f, KEu = 0.0328250f, KEx = 1.0201f;
constexpr float KIv = 0.9898f, KIu = 0.1122000f, KIx = 0.2601f;

__device__ __forceinline__ float fexp2(float x){ return __builtin_amdgcn_exp2f(x); }
__device__ __forceinline__ float flog2(float x){ return __builtin_amdgcn_logf(x); }
__device__ __forceinline__ float frcp (float x){ return __builtin_amdgcn_rcpf(x); }

__device__ __forceinline__ float sigf(float x){
    return 5.0f * frcp(1.0f + fexp2(fmaf(-RL2E, x, V0R)));
}
__device__ __forceinline__ float tanh500(float x){
    return 500.0f - 1000.0f * frcp(1.0f + fexp2(x * TU_));
}
__device__ __forceinline__ float satf(float x){
    return 1000.0f - 2000.0f * frcp(1.0f + fexp2(x * TS_));
}
__device__ __forceinline__ float wl_f(const float* __restrict__ wbb,
                                      const float* __restrict__ sc,
                                      int i, int j){
    float w0 = fexp2(wbb[i*N_+j]*L2E) * sc[i*N_+j];
    float w1 = fexp2(wbb[j*N_+i]*L2E) * sc[j*N_+i];
    return flog2(1.0f + 0.5f*(w0+w1)) * LN2;
}

// R10: 2 inner steps per barrier, REGISTER-MINIMAL lookahead.
// Lesson from R8/R9: the compiler pins this kernel at 64 VGPRs; any +10 live
// registers in a hot role spills to scratch (WRITE_SIZE 633->715->777 KB) and
// costs more than the barriers save. The 1-step M lookahead is only
//   Mp1 = satf(fmaf(DT,Mv,M))        [2 instructions, no transcendentals]
// so rows publish float2 (M_h, M_{h+1}); CSR consumers serve 2 steps from one
// ds_read_b64. Barriers/outer 22 -> 12, row DS-instr/outer ~300 -> ~140.
__global__ void __launch_bounds__(NT_)
jansen_kernel(
    const float* __restrict__ input,     // (N,H,B)
    const float* __restrict__ noise_in,  // (N,H,B,3)
    const float* __restrict__ hx,        // (N,6)
    const float* __restrict__ hEin,      // (N,500)
    const float* __restrict__ wbb,       // (N,N)
    const float* __restrict__ lm,        // (64,N)
    const float* __restrict__ sc,        // (N,N)
    const int*   __restrict__ dist,      // (N,N)
    float* __restrict__ out,             // 64*400 eeg + N*6 state
    float2* __restrict__ tab)            // d_ws: 40000 x (w, meta)
{
    __shared__ float  histT[N_*HS_];         // transposed circular M history
    __shared__ float2 une2[H_*N_];           // (u,ne), layout: [(h>>1)*N+i]*2+(h&1)
    __shared__ float2 mpub[2*N_];            // ping-pong (M_h, M_{h+1})
    __shared__ float  d0w_l[CAP*N_];         // d==0 CSR weights (SoA)
    __shared__ unsigned char d0j_l[CAP*N_];  // d==0 CSR j (u8)
    __shared__ float  d1w_l[CAP*N_];         // d==1 CSR weights
    __shared__ unsigned char d1j_l[CAP*N_];  // d==1 CSR j
    __shared__ float  led_part[4*N_];        // static-gather partials
    __shared__ float  emi[N_];
    __shared__ float  colmean[N_];
    __shared__ float  lmrs[OUT_];
    __shared__ float  red_s[NT_/64];
    __shared__ float  norm_s;

    const int t = threadIdx.x;
    const bool isr = (t < N_);
    const bool isg = (t >= GT0);             // 800 gather threads
    const int  gt  = t - GT0;                // 0..799
    const int  grow  = gt >> 2;              // row 0..199
    const int  gslot = gt & 3;               // slot 0..3
    const int  jbase = gslot * EPT;          // this thread's first j
    const int  tb    = gt * EPT;             // table base index

    int sidx[5];                             // slab LDS float2-indices (gather)
    int goff[5];                             // slab global offsets sans sn

    // ===== S0: lmrs + state/hist init + initial slab + initial publish =====
    if (t < OUT_){
        float s2 = 0.f;
        for (int j=0;j<N_;++j) s2 += fabsf(lm[t*N_+j]);
        lmrs[t] = s2;
    }
    float M=0,E=0,I=0,Mv=0,Ev=0,Iv=0, rowsum=0, ledst=0;
    int cnt0=0, cnt1=0;
    #pragma unroll
    for (int r=0;r<5;++r){ sidx[r]=0; goff[r]=0; }
    if (isg){
        #pragma unroll
        for (int r=0;r<5;++r){
            int p = r*NG_ + gt;
            int hh = p / N_, ii = p - hh*N_;
            sidx[r] = ((hh>>1)*N_ + ii)*2 + (hh&1);
            goff[r] = ii*(H_*B_) + hh*B_;
            une2[sidx[r]] = make_float2(input[goff[r]], noise_in[goff[r]*3]);
        }
    }
    if (isr){
        // initial hEb col k (k=1..49) -> slot (0-k) mod 50 = 50-k
        for (int k=1;k<HD_;++k) histT[t*HS_ + (HD_-k)] = hEin[t*BUF_+k];
        M=hx[t*6+0]; E=hx[t*6+1]; I=hx[t*6+2];
        Mv=hx[t*6+3]; Ev=hx[t*6+4]; Iv=hx[t*6+5];
        // publish for s=0 interval 0: step0 col0 = hE[:,0] (quirk),
        // step1 col0 = M_end(step0) = satf(fmaf(DT,Mv,M)) from hx state
        mpub[t] = make_float2(hEin[t*BUF_], satf(fmaf(DT_, Mv, M)));
    }
    __syncthreads();

    // ===== S1: compute wl entries -> RAW table; Frobenius + rowsum =====
    float ss = 0.f, rs = 0.f;
    for (int m=0;m<EPT;++m){
        float w = 0.f; int d = 2;
        int j = jbase + m;
        if (isg){
            d = dist[j*N_+grow] >> 1;        // delays[j][grow]
            w = wl_f(wbb, sc, grow, j);
        }
        ss = fmaf(w,w,ss); rs += w;
        if (isg){
            int dm = (d<2) ? 2 : d;          // d<2 handled by CSRs
            float ws = (d>=2) ? w : 0.f;
            tab[tb+m] = make_float2(ws, __uint_as_float((unsigned)j | ((unsigned)dm<<16)));
        }
    }
    if (isr){                                 // colmean (needs lmrs)
        float cm=0.f;
        for (int o=0;o<OUT_;++o) cm += lm[o*N_+t] * frcp(lmrs[o]);
        colmean[t] = cm * (1.0f/(float)OUT_);
    }
    #pragma unroll
    for (int o=32;o>0;o>>=1) ss += __shfl_down(ss,o,64);
    if ((t&63)==0) red_s[t>>6] = ss;
    __syncthreads();
    if (t==0){ float tot=0.f; for (int w=0;w<NT_/64;++w) tot+=red_s[w]; norm_s = sqrtf(tot); }
    __syncthreads();
    const float inv = 1.0f / norm_s;
    if (isg){
        float* tf = (float*)tab;
        for (int m=0;m<EPT;++m) tf[2*(tb+m)] *= inv;
    }
    if (isg) led_part[gslot*N_+grow] = rs;    // raw rowsum partial

    // ===== S3: row CSR build (d<2), registers for d0 =====
    float dw[UNR]; unsigned jpk[3];
    #pragma unroll
    for (int k=0;k<UNR;++k) dw[k] = 0.f;
    jpk[0]=jpk[1]=jpk[2]=0u;
    if (isr){
        #pragma unroll
        for (int k=0;k<UNR;++k){ d0w_l[k*N_+t]=0.f; d0j_l[k*N_+t]=0;
                                 d1w_l[k*N_+t]=0.f; d1j_l[k*N_+t]=0; }
        for (int j=0;j<N_;++j){
            int dd = dist[j*N_+t] >> 1;
            if (dd < 2){
                float w = wl_f(wbb, sc, t, j) * inv;
                if (dd==0){ if (cnt0<CAP){ d0w_l[cnt0*N_+t]=w; d0j_l[cnt0*N_+t]=(unsigned char)j; ++cnt0; } }
                else      { if (cnt1<CAP){ d1w_l[cnt1*N_+t]=w; d1j_l[cnt1*N_+t]=(unsigned char)j; ++cnt1; } }
            }
        }
        #pragma unroll
        for (int k=0;k<UNR;++k){
            dw[k] = d0w_l[k*N_+t];
            unsigned jv = d0j_l[k*N_+t];
            jpk[k>>2] |= jv << ((k&3)*8);
        }
    }
    __syncthreads();

    // ===== S4: rowsum =====
    if (isr){
        rowsum = (led_part[t]+led_part[N_+t]+led_part[2*N_+t]+led_part[3*N_+t]) * inv;
    }
    __syncthreads();

    // ===== S5: initial static gather for s=0 (target step 0 -> c = 50-d) =====
    if (isg){
        float a0 = 0.f;
        for (int m=0;m<EPT;++m){
            float2 e = tab[tb+m];
            unsigned um = __float_as_uint(e.y);
            int c = HD_ - (int)(um>>16);     // d in [2,49] -> c in [1,48]
            a0 = fmaf(e.x, histT[(um&0xFFFFu)*HS_ + c], a0);
        }
        led_part[gslot*N_+grow] = a0;
    }
    __syncthreads();

    // ===== S6: initial ledst (+ d==1 from hE col 1 = slot 49) =====
    if (isr){
        float v = led_part[t]+led_part[N_+t]+led_part[2*N_+t]+led_part[3*N_+t];
        #pragma unroll
        for (int k=0;k<UNR;++k)
            v = fmaf(d1w_l[k*N_+t], histT[(int)d1j_l[k*N_+t]*HS_ + (HD_-1)], v);
        for (int k=UNR;k<cnt1;++k)
            v = fmaf(d1w_l[k*N_+t], histT[(int)d1j_l[k*N_+t]*HS_ + (HD_-1)], v);
        ledst = v;
    }
    __syncthreads();

// one ODE inner step; LEd given, (u,ne) as two floats
#define STEP(LEDV, UU, NN) do{                                               \
    float rM  = sigf(E - I);                                                 \
    float uM  = tanh500(rM);                                                 \
    float Mn  = satf(fmaf(DT_, Mv, M));                                      \
    float Mvn = satf(fmaf(KMv, Mv, fmaf(KMu, uM, -KMx*M)));                  \
    float rI  = C4_*sigf(C3_*M);                                             \
    float uI  = tanh500(rI);                                                 \
    float In  = satf(fmaf(DT_, Iv, I));                                      \
    float Ivn = satf(fmaf(KIv, Iv, fmaf(KIu, uI, -KIx*I)));                  \
    float rE  = fmaf(STD_, (NN), G_*((LEDV) - rowsum*E)) + C2_*sigf(C1_*M);  \
    float uE  = fmaf(K_, (UU), tanh500(rE));                                 \
    float En  = satf(fmaf(DT_, Ev, E));                                      \
    float Evn = satf(fmaf(KEv, Ev, fmaf(KEu, uE, -KEx*E)));                  \
    M=Mn; Mv=Mvn; I=In; Iv=Ivn; E=En; Ev=Evn;                                \
}while(0)

    // ===== main loop: 400 outer x 10 intervals x 2 steps =====
    int smod = 0;
    int pp = 0;                              // mpub buffer with current publish
    for (int s=0; s<B_; ++s){
        int ts = smod+1; if (ts==HD_) ts = 0;      // (s+1) % 50
        float acc = 0.f;
        for (int q=0; q<10; ++q){
            // --- gather: 5 static entries for outer step s+1 ---
            if (isg){
                #pragma unroll
                for (int k=0;k<5;++k){
                    float2 e = tab[tb + 5*q + k];
                    unsigned um = __float_as_uint(e.y);
                    int c = ts - (int)(um>>16); if (c<0) c += HD_;
                    acc = fmaf(e.x, histT[(um&0xFFFFu)*HS_ + c], acc);
                }
            }
            if (isr){
                const float2* sr = &mpub[pp*N_];
                float2*       sw = &mpub[(pp^1)*N_];
                float4 un01 = ((const float4*)une2)[q*N_ + t];
                // CSR pass: one b64 per entry serves both steps (2-way split
                // keeps R7's summation order for each step)
                float lA0=0.f,lA1=0.f,lB0=0.f,lB1=0.f;
                #pragma unroll
                for (int k=0;k<UNR;++k){
                    int j = (jpk[k>>2] >> ((k&3)*8)) & 255;
                    float w = dw[k];
                    float2 sj = sr[j];
                    if (k&1){ lA1 = fmaf(w, sj.x, lA1); lB1 = fmaf(w, sj.y, lB1); }
                    else    { lA0 = fmaf(w, sj.x, lA0); lB0 = fmaf(w, sj.y, lB0); }
                }
                for (int k=UNR;k<cnt0;++k){
                    float w = d0w_l[k*N_+t];
                    float2 sj = sr[d0j_l[k*N_+t]];
                    lA0 = fmaf(w, sj.x, lA0); lB0 = fmaf(w, sj.y, lB0);
                }
                STEP(ledst + (lA0+lA1), un01.x, un01.y);
                STEP(ledst + (lB0+lB1), un01.z, un01.w);
                // publish (M_h, M_{h+1}) for next interval — Mp1 replicates
                // bitwise the op the next STEP will perform
                sw[t] = make_float2(M, satf(fmaf(DT_, Mv, M)));
            }
            __syncthreads();
            pp ^= 1;
        }
        // ===== outer boundary =====
        if (isr){ histT[t*HS_ + smod] = M; emi[t] = E - I; }
        if (isg){
            led_part[gslot*N_+grow] = acc;
            // stage (u,ne) slab for s+1 (one L2 drain per outer step)
            int sn = s+1; if (sn >= B_) sn = B_-1;
            #pragma unroll
            for (int r=0;r<5;++r){
                une2[sidx[r]] = make_float2(input[goff[r] + sn],
                                            noise_in[(goff[r] + sn)*3]);
            }
        }
        __syncthreads();
        if (isr){
            float v = led_part[t]+led_part[N_+t]+led_part[2*N_+t]+led_part[3*N_+t];
            // d==1 term for outer s+1: M_end(s) = histT slot smod (just written)
            #pragma unroll
            for (int k=0;k<UNR;++k)
                v = fmaf(d1w_l[k*N_+t], histT[(int)d1j_l[k*N_+t]*HS_ + smod], v);
            for (int k=UNR;k<cnt1;++k)
                v = fmaf(d1w_l[k*N_+t], histT[(int)d1j_l[k*N_+t]*HS_ + smod], v);
            ledst = v;
        }
        {   // eeg
            int o = t>>4, l = t&15;
            float il = frcp(lmrs[o]);
            float a2 = 0.f;
            for (int j=l;j<N_;j+=16)
                a2 = fmaf(fmaf(lm[o*N_+j], il, -colmean[j]), emi[j], a2);
            a2 += __shfl_down(a2,8,16); a2 += __shfl_down(a2,4,16);
            a2 += __shfl_down(a2,2,16); a2 += __shfl_down(a2,1,16);
            if (l==0) out[o*B_+s] = fmaf(CY0_, a2, -Y0_);
        }
        smod = ts;
        __syncthreads();
    }

#undef STEP

    // final state
    if (isr){
        float* cs = out + OUT_*B_ + t*6;
        cs[0]=M; cs[1]=E; cs[2]=I; cs[3]=Mv; cs[4]=Ev; cs[5]=Iv;
    }
}

} // namespace

extern "C" void kernel_launch(void* const* d_in, const int* in_sizes, int n_in,
                              void* d_out, int out_size, void* d_ws, size_t ws_size,
                              hipStream_t stream)
{
    const float* input    = (const float*)d_in[0];
    const float* noise_in = (const float*)d_in[1];
    const float* hx   = (const float*)d_in[3];
    const float* hEin = (const float*)d_in[4];
    const float* wbb  = (const float*)d_in[5];
    const float* lm   = (const float*)d_in[6];
    const float* sc   = (const float*)d_in[7];
    const int*   dist = (const int*)d_in[8];
    float* out = (float*)d_out;
    float2* tab = (float2*)((char*)d_ws + 1024);   // 40000 x 8B = 320KB

    hipLaunchKernelGGL(jansen_kernel, dim3(1), dim3(NT_), 0, stream,
                       input, noise_in, hx, hEin, wbb, lm, sc, dist, out, tab);
}

// Round 11
// 6689.759 us; speedup vs baseline: 1.7225x; 1.1135x over previous
//
#include <hip/hip_runtime.h>
#include <math.h>

namespace {

constexpr int N_   = 200;   // nodes
constexpr int H_   = 20;    // inner steps
constexpr int B_   = 400;   // outer steps
constexpr int OUT_ = 64;    // eeg channels
constexpr int BUF_ = 500;   // hE buffer length
constexpr int NT_  = 256;   // threads per block (4 waves)
constexpr int HD_  = 50;    // history depth (max delay 49)
constexpr int HS_  = 51;    // transposed history stride
constexpr int EPT  = 50;    // entries per gather thread
constexpr int CAP  = 16;    // CSR capacity (d==0 / d==1)
constexpr int UNR  = 12;    // unrolled CSR entries

constexpr float L2E = 1.4426950408889634f;
constexpr float LN2 = 0.6931471805599453f;

constexpr float DT_  = 0.0001f;
constexpr float G_   = 1000.01f;
constexpr float C1_  = 135.01f;
constexpr float C2_  = 108.01f;
constexpr float C3_  = 33.76f;
constexpr float C4_  = 33.76f;
constexpr float STD_ = 250.0f;
constexpr float K_   = 5.5f;
constexpr float CY0_ = 5.0f;
constexpr float Y0_  = 2.0f;

constexpr float RL2E = 0.56f * L2E;
constexpr float V0R  = 6.0f * RL2E;
constexpr float TU_  = 2.0f * L2E / 500.0f;
constexpr float TS_  = 2.0f * L2E / 1000.0f;

constexpr float KMv = 0.9798f, KMu = 0.0328250f, KMx = 1.0201f;
constexpr float KEv = 0.9798f, KEu = 0.0328250f, KEx = 1.0201f;
constexpr float KIv = 0.9898f, KIu = 0.1122000f, KIx = 0.2601f;

__device__ __forceinline__ float fexp2(float x){ return __builtin_amdgcn_exp2f(x); }
__device__ __forceinline__ float flog2(float x){ return __builtin_amdgcn_logf(x); }
__device__ __forceinline__ float frcp (float x){ return __builtin_amdgcn_rcpf(x); }

__device__ __forceinline__ float sigf(float x){
    return 5.0f * frcp(1.0f + fexp2(fmaf(-RL2E, x, V0R)));
}
__device__ __forceinline__ float tanh500(float x){
    return 500.0f - 1000.0f * frcp(1.0f + fexp2(x * TU_));
}
__device__ __forceinline__ float satf(float x){
    return 1000.0f - 2000.0f * frcp(1.0f + fexp2(x * TS_));
}
__device__ __forceinline__ float wl_f(const float* __restrict__ wbb,
                                      const float* __restrict__ sc,
                                      int i, int j){
    float w0 = fexp2(wbb[i*N_+j]*L2E) * sc[i*N_+j];
    float w1 = fexp2(wbb[j*N_+i]*L2E) * sc[j*N_+i];
    return flog2(1.0f + 0.5f*(w0+w1)) * LN2;
}

__device__ __forceinline__ int ld_acq(const int* p){
    return __hip_atomic_load(p, __ATOMIC_ACQUIRE, __HIP_MEMORY_SCOPE_AGENT);
}
__device__ __forceinline__ void st_rel(int* p, int v){
    __hip_atomic_store(p, v, __ATOMIC_RELEASE, __HIP_MEMORY_SCOPE_AGENT);
}
__device__ __forceinline__ float ld_rf(const float* p){
    return __hip_atomic_load(p, __ATOMIC_RELAXED, __HIP_MEMORY_SCOPE_AGENT);
}
__device__ __forceinline__ void st_rf(float* p, float v){
    __hip_atomic_store(p, v, __ATOMIC_RELAXED, __HIP_MEMORY_SCOPE_AGENT);
}
#define WAIT_GE(P, V) while (ld_acq(P) < (V)) __builtin_amdgcn_s_sleep(8)

// R11: 5 blocks x 256 threads. Block 0 = row solver (4-wave barriers, no
// gather interference). Blocks 1..4 = gather engines, each owning slot b-1
// (50 entries/row) with a private histT copy. Protocol: rows publish
// M_end(s)+rflag=s+1 each boundary; gather block computes led(s+1) during
// outer s (needs only M_end(s-1)) and publishes gflag[b]=s+1 — rows' polls
// are satisfied in steady state. Poison 0xAAAAAAAA is negative as int, so
// all waits are "< target" safe. 256-thr blocks = 1 wave/EU -> no 64-VGPR
// spill wall (the disease of R8/R9).
__global__ void __launch_bounds__(NT_)
jansen_kernel(
    const float* __restrict__ input,     // (N,H,B)
    const float* __restrict__ noise_in,  // (N,H,B,3)
    const float* __restrict__ hx,        // (N,6)
    const float* __restrict__ hEin,      // (N,500)
    const float* __restrict__ wbb,       // (N,N)
    const float* __restrict__ lm,        // (64,N)
    const float* __restrict__ sc,        // (N,N)
    const int*   __restrict__ dist,      // (N,N)
    float* __restrict__ out,             // 64*400 eeg + N*6 state
    int*    flags,                       // [0]=rflag, [1..4]=gflag, [8..11]=sflag
    float*  ssq,                         // [4]
    float2* tab,                         // 40000 x (w, meta)
    float*  rs_part,                     // [800] slot-major rowsum partials
    float*  led_g,                       // [2][800] ping-pong led partials
    float*  mvec)                        // [200] M_end(s)
{
    __shared__ __align__(16) char smem[45056];
    const int t = threadIdx.x;
    int* rflag = flags;
    int* gflag = flags + 1;
    int* sflag = flags + 8;

    if (blockIdx.x > 0){
        // ================= gather block, slot = b-1 =================
        const int slot = (int)blockIdx.x - 1;
        float* histT = (float*)smem;                    // 200*51 floats
        float* redg  = (float*)(smem + 40800);          // 4 floats
        const bool a = (t < N_);
        const int  tb = (4*t + slot)*EPT;

        // ---- setup: wl for this slot's 50 entries per row t ----
        float ss = 0.f, rs = 0.f;
        if (a){
            for (int m=0;m<EPT;++m){
                int j = slot*EPT + m;
                int d = dist[j*N_ + t] >> 1;            // delays[j][t]
                float w = wl_f(wbb, sc, t, j);
                ss = fmaf(w,w,ss); rs += w;
                int dm = (d<2) ? 2 : d;
                tab[tb+m] = make_float2((d>=2)?w:0.f,
                            __uint_as_float((unsigned)j | ((unsigned)dm<<16)));
            }
            st_rf(&rs_part[slot*N_ + t], rs);
        }
        #pragma unroll
        for (int o=32;o>0;o>>=1) ss += __shfl_down(ss,o,64);
        if ((t&63)==0) redg[t>>6] = ss;
        __syncthreads();
        if (t==0){
            float tot = ((redg[0]+redg[1])+redg[2])+redg[3];
            st_rf(&ssq[slot], tot);
            st_rel(&sflag[slot], 1);
        }
        WAIT_GE(&sflag[0],1); WAIT_GE(&sflag[1],1);
        WAIT_GE(&sflag[2],1); WAIT_GE(&sflag[3],1);
        const float nrm = sqrtf(((ld_rf(&ssq[0])+ld_rf(&ssq[1]))
                                 +ld_rf(&ssq[2]))+ld_rf(&ssq[3]));
        const float inv = 1.0f / nrm;
        if (a){
            float* tf = (float*)tab;
            for (int m=0;m<EPT;++m) tf[2*(tb+m)] *= inv;
            // initial hist overlay: hE col k -> slot 50-k ("M_end(-k)")
            for (int k=1;k<HD_;++k) histT[t*HS_ + (HD_-k)] = hEin[t*BUF_+k];
        }
        __syncthreads();
        // ---- led(0) and led(1) from initial history only ----
        #pragma unroll
        for (int T=0; T<2; ++T){
            if (a){
                float acc = 0.f;
                for (int m=0;m<EPT;++m){
                    float2 e = tab[tb+m];
                    unsigned um = __float_as_uint(e.y);
                    int c = T - (int)(um>>16); if (c<0) c += HD_;
                    acc = fmaf(e.x, histT[(um&0xFFFFu)*HS_ + c], acc);
                }
                st_rf(&led_g[(T&1)*800 + slot*N_ + t], acc);
            }
            __syncthreads();
            if (t==0) st_rel(&gflag[slot], T);
        }
        // ---- main: led(T) for T=2..399, consuming M_end(T-2) ----
        int cw = 0;                       // (T-2) % 50
        int cT = 2;                       // T % 50
        for (int T=2; T<B_; ++T){
            WAIT_GE(rflag, T-1);
            if (a) histT[t*HS_ + cw] = ld_rf(&mvec[t]);
            __syncthreads();
            if (a){
                float acc = 0.f;
                for (int m=0;m<EPT;++m){
                    float2 e = tab[tb+m];
                    unsigned um = __float_as_uint(e.y);
                    int c = cT - (int)(um>>16); if (c<0) c += HD_;
                    acc = fmaf(e.x, histT[(um&0xFFFFu)*HS_ + c], acc);
                }
                st_rf(&led_g[(T&1)*800 + slot*N_ + t], acc);
            }
            __syncthreads();
            if (t==0) st_rel(&gflag[slot], T);
            ++cw; if (cw==HD_) cw = 0;
            ++cT; if (cT==HD_) cT = 0;
        }
        return;
    }

    // ================= row block =================
    float*         mcol    = (float*)smem;                    // 2*200
    float*         emi     = (float*)(smem + 1600);           // 200
    float*         colmean = (float*)(smem + 2400);           // 200
    float*         lmrs    = (float*)(smem + 3200);           // 64
    float*         d0w_l   = (float*)(smem + 3456);           // 16*200
    unsigned char* d0j_l   = (unsigned char*)(smem + 16256);  // 16*200
    float*         d1w_l   = (float*)(smem + 19456);          // 16*200
    unsigned char* d1j_l   = (unsigned char*)(smem + 32256);  // 16*200

    const bool isr = (t < N_);
    float M=0,E=0,I=0,Mv=0,Ev=0,Iv=0, rowsum=0, ledst=0, u_cur=0, ne_cur=0;
    int cnt0=0, cnt1=0, ubase=0;

    if (t < OUT_){
        float s2 = 0.f;
        for (int j=0;j<N_;++j) s2 += fabsf(lm[t*N_+j]);
        lmrs[t] = s2;
    }
    if (isr){
        mcol[t] = hEin[t*BUF_];          // first col-0 read is hE[:,0]
        M=hx[t*6+0]; E=hx[t*6+1]; I=hx[t*6+2];
        Mv=hx[t*6+3]; Ev=hx[t*6+4]; Iv=hx[t*6+5];
        ubase = t*(H_*B_);
        u_cur  = input[ubase];
        ne_cur = noise_in[ubase*3];
    }
    __syncthreads();
    if (isr){
        float cm=0.f;
        for (int o=0;o<OUT_;++o) cm += lm[o*N_+t] * frcp(lmrs[o]);
        colmean[t] = cm * (1.0f/(float)OUT_);
    }
    // norm from gather blocks
    WAIT_GE(&sflag[0],1); WAIT_GE(&sflag[1],1);
    WAIT_GE(&sflag[2],1); WAIT_GE(&sflag[3],1);
    const float nrm = sqrtf(((ld_rf(&ssq[0])+ld_rf(&ssq[1]))
                             +ld_rf(&ssq[2]))+ld_rf(&ssq[3]));
    const float inv = 1.0f / nrm;

    // CSR build (d<2)
    float dw[UNR]; unsigned jpk[3];
    #pragma unroll
    for (int k=0;k<UNR;++k) dw[k] = 0.f;
    jpk[0]=jpk[1]=jpk[2]=0u;
    if (isr){
        #pragma unroll
        for (int k=0;k<UNR;++k){ d0w_l[k*N_+t]=0.f; d0j_l[k*N_+t]=0;
                                 d1w_l[k*N_+t]=0.f; d1j_l[k*N_+t]=0; }
        for (int j=0;j<N_;++j){
            int dd = dist[j*N_+t] >> 1;
            if (dd < 2){
                float w = wl_f(wbb, sc, t, j) * inv;
                if (dd==0){ if (cnt0<CAP){ d0w_l[cnt0*N_+t]=w; d0j_l[cnt0*N_+t]=(unsigned char)j; ++cnt0; } }
                else      { if (cnt1<CAP){ d1w_l[cnt1*N_+t]=w; d1j_l[cnt1*N_+t]=(unsigned char)j; ++cnt1; } }
            }
        }
        #pragma unroll
        for (int k=0;k<UNR;++k){
            dw[k] = d0w_l[k*N_+t];
            unsigned jv = d0j_l[k*N_+t];
            jpk[k>>2] |= jv << ((k&3)*8);
        }
        rowsum = (((ld_rf(&rs_part[t]) + ld_rf(&rs_part[N_+t]))
                   + ld_rf(&rs_part[2*N_+t])) + ld_rf(&rs_part[3*N_+t])) * inv;
    }
    // initial ledst: led(0) static + d==1 from hE col 1
    WAIT_GE(&gflag[0],0); WAIT_GE(&gflag[1],0);
    WAIT_GE(&gflag[2],0); WAIT_GE(&gflag[3],0);
    if (isr){
        float v = ((ld_rf(&led_g[t]) + ld_rf(&led_g[N_+t]))
                   + ld_rf(&led_g[2*N_+t])) + ld_rf(&led_g[3*N_+t]);
        #pragma unroll
        for (int k=0;k<UNR;++k)
            v = fmaf(d1w_l[k*N_+t], hEin[(int)d1j_l[k*N_+t]*BUF_ + 1], v);
        for (int k=UNR;k<cnt1;++k)
            v = fmaf(d1w_l[k*N_+t], hEin[(int)d1j_l[k*N_+t]*BUF_ + 1], v);
        ledst = v;
    }
    __syncthreads();

    // ===== main loop: 400 outer x 20 inner, 4-wave barriers =====
    for (int s=0; s<B_; ++s){
        for (int h=0; h<H_; ++h){
            if (isr){
                float u = u_cur, ne = ne_cur;
                int hn = h+1, sn = s;
                if (hn==H_){ hn=0; sn = (s+1<B_)? s+1 : s; }
                int idx = ubase + hn*B_ + sn;
                u_cur  = input[idx];             // prefetch next step
                ne_cur = noise_in[idx*3];
                // M-path first
                float rM  = sigf(E - I);
                float uM  = tanh500(rM);
                float Mn  = satf(fmaf(DT_, Mv, M));
                float Mvn = satf(fmaf(KMv, Mv, fmaf(KMu, uM, -KMx*M)));
                mcol[((h&1)^1)*N_ + t] = Mn;
                // I-path
                float rI  = C4_*sigf(C3_*M);
                float uI  = tanh500(rI);
                float In  = satf(fmaf(DT_, Iv, I));
                float Ivn = satf(fmaf(KIv, Iv, fmaf(KIu, uI, -KIx*I)));
                // E-path
                const float* mc = &mcol[(h&1)*N_];
                float l0 = ledst, l1 = 0.f, l2 = 0.f, l3 = 0.f;
                #pragma unroll
                for (int k=0;k<UNR;++k){
                    int j = (jpk[k>>2] >> ((k&3)*8)) & 255;
                    float v = mc[j];
                    if      ((k&3)==0) l0 = fmaf(dw[k], v, l0);
                    else if ((k&3)==1) l1 = fmaf(dw[k], v, l1);
                    else if ((k&3)==2) l2 = fmaf(dw[k], v, l2);
                    else               l3 = fmaf(dw[k], v, l3);
                }
                for (int k=UNR;k<cnt0;++k)
                    l0 = fmaf(d0w_l[k*N_+t], mc[d0j_l[k*N_+t]], l0);
                float LEd = (l0+l1)+(l2+l3);
                float rE  = fmaf(STD_, ne, G_*(LEd - rowsum*E)) + C2_*sigf(C1_*M);
                float uE  = fmaf(K_, u, tanh500(rE));
                float En  = satf(fmaf(DT_, Ev, E));
                float Evn = satf(fmaf(KEv, Ev, fmaf(KEu, uE, -KEx*E)));
                M=Mn; Mv=Mvn; I=In; Iv=Ivn; E=En; Ev=Evn;
            }
            __syncthreads();
        }
        // ===== boundary =====
        if (isr){ emi[t] = E - I; st_rf(&mvec[t], M); }
        __syncthreads();
        if (t==0) st_rel(rflag, s+1);    // M_end(s) published
        {   // eeg: 4 lanes per output row
            int o = t>>2, l = t&3;
            float il = frcp(lmrs[o]);
            float a2 = 0.f;
            for (int j=l;j<N_;j+=4)
                a2 = fmaf(fmaf(lm[o*N_+j], il, -colmean[j]), emi[j], a2);
            a2 += __shfl_down(a2,2,4);
            a2 += __shfl_down(a2,1,4);
            if (l==0) out[o*B_+s] = fmaf(CY0_, a2, -Y0_);
        }
        if (s+1 < B_){
            WAIT_GE(&gflag[0], s+1); WAIT_GE(&gflag[1], s+1);
            WAIT_GE(&gflag[2], s+1); WAIT_GE(&gflag[3], s+1);
            if (isr){
                const float* lg = led_g + ((s+1)&1)*800;
                float v = ((ld_rf(&lg[t]) + ld_rf(&lg[N_+t]))
                           + ld_rf(&lg[2*N_+t])) + ld_rf(&lg[3*N_+t]);
                // d==1 term: M_end(s) = mcol buffer 0 (H even)
                #pragma unroll
                for (int k=0;k<UNR;++k)
                    v = fmaf(d1w_l[k*N_+t], mcol[d1j_l[k*N_+t]], v);
                for (int k=UNR;k<cnt1;++k)
                    v = fmaf(d1w_l[k*N_+t], mcol[d1j_l[k*N_+t]], v);
                ledst = v;
            }
        }
    }

    // final state
    if (isr){
        float* cs = out + OUT_*B_ + t*6;
        cs[0]=M; cs[1]=E; cs[2]=I; cs[3]=Mv; cs[4]=Ev; cs[5]=Iv;
    }
}

} // namespace

extern "C" void kernel_launch(void* const* d_in, const int* in_sizes, int n_in,
                              void* d_out, int out_size, void* d_ws, size_t ws_size,
                              hipStream_t stream)
{
    const float* input    = (const float*)d_in[0];
    const float* noise_in = (const float*)d_in[1];
    const float* hx   = (const float*)d_in[3];
    const float* hEin = (const float*)d_in[4];
    const float* wbb  = (const float*)d_in[5];
    const float* lm   = (const float*)d_in[6];
    const float* sc   = (const float*)d_in[7];
    const int*   dist = (const int*)d_in[8];
    float* out = (float*)d_out;

    char* ws = (char*)d_ws;
    int*    flags   = (int*)ws;                       // 64 ints
    float*  ssq     = (float*)(ws + 256);             // 4 floats
    float2* tab     = (float2*)(ws + 1024);           // 320000 B
    float*  rs_part = (float*)(ws + 1024 + 320000);   // 800 floats
    float*  led_g   = rs_part + 800;                  // 1600 floats
    float*  mvec    = led_g + 1600;                   // 200 floats

    hipLaunchKernelGGL(jansen_kernel, dim3(5), dim3(NT_), 0, stream,
                       input, noise_in, hx, hEin, wbb, lm, sc, dist, out,
                       flags, ssq, tab, rs_part, led_g, mvec);
}